// Round 5
// baseline (805.906 us; speedup 1.0000x reference)
//
#include <hip/hip_runtime.h>
#include <hip/hip_bf16.h>
#include <cstdint>
#include <cstddef>

// ---------- types ----------
typedef __attribute__((ext_vector_type(8))) short short8;   // bf16 x8 (4 VGPRs)
typedef __attribute__((ext_vector_type(4))) short short4v;  // bf16 x4
typedef __attribute__((ext_vector_type(16))) float floatx16;

#define D_MODEL 512
#define HDIM    2048
#define TSEQ    16384
#define NTOK    65536   // B*T = 4*16384

// ---------- helpers ----------
__device__ __forceinline__ float bf2f(short s) {
  union { unsigned u; float f; } v; v.u = ((unsigned)(unsigned short)s) << 16; return v.f;
}
__device__ __forceinline__ short f2bf(float f) {
  union { float fv; unsigned u; } v; v.fv = f;
  unsigned u = v.u;
  u += 0x7FFFu + ((u >> 16) & 1u);   // RNE
  return (short)(u >> 16);
}
__device__ __forceinline__ void gload_lds16(const void* g, void* l) {
  // width=16 async global->LDS; LDS dest = wave-uniform base + lane*16 (m104)
  __builtin_amdgcn_global_load_lds((const __attribute__((address_space(1))) void*)g,
                                   (__attribute__((address_space(3))) void*)l, 16, 0, 0);
}

// ---------- weight convert + transpose: W[K][N] f32 -> Wt[N][K] bf16 ----------
__global__ void wt_transpose(const float* __restrict__ W, short* __restrict__ Wt,
                             const int K, const int N) {
  __shared__ float t[64][65];
  const int tid = threadIdx.x;
  const long k0 = (long)blockIdx.x * 64;
  const long n0 = (long)blockIdx.y * 64;
  const int rr = tid >> 4;
  const int cc = (tid & 15) * 4;
#pragma unroll
  for (int i = 0; i < 4; ++i) {
    const int r = rr + i * 16;
    const float4 v = *(const float4*)(W + (k0 + r) * N + n0 + cc);
    t[r][cc + 0] = v.x; t[r][cc + 1] = v.y; t[r][cc + 2] = v.z; t[r][cc + 3] = v.w;
  }
  __syncthreads();
#pragma unroll
  for (int i = 0; i < 4; ++i) {
    const int n = rr + i * 16;
    short4v o;
    o[0] = f2bf(t[cc + 0][n]);
    o[1] = f2bf(t[cc + 1][n]);
    o[2] = f2bf(t[cc + 2][n]);
    o[3] = f2bf(t[cc + 3][n]);
    *(short4v*)(Wt + (n0 + n) * K + k0 + cc) = o;
  }
}

// conv_w [512][17] f32 -> wT [17][512] f32
__global__ void convw_transpose(const float* __restrict__ cw, float* __restrict__ wT) {
  const int idx = blockIdx.x * 256 + threadIdx.x;
  if (idx >= 17 * D_MODEL) return;
  const int k = idx / D_MODEL;
  const int c = idx % D_MODEL;
  wT[idx] = cw[c * 17 + k];
}

// ---------- RMSNorm: one wave per row, f32 in -> bf16 out ----------
__global__ void rmsnorm_kernel(const float* __restrict__ x, const float* __restrict__ w,
                               short* __restrict__ outp) {
  const int lane = threadIdx.x & 63;
  const long row = (long)blockIdx.x * 4 + (threadIdx.x >> 6);
  const float* xr = x + row * D_MODEL + lane * 8;
  const float4 a = *(const float4*)xr;
  const float4 b = *(const float4*)(xr + 4);
  float ss = a.x * a.x + a.y * a.y + a.z * a.z + a.w * a.w
           + b.x * b.x + b.y * b.y + b.z * b.z + b.w * b.w;
#pragma unroll
  for (int m = 32; m; m >>= 1) ss += __shfl_xor(ss, m);
  const float scale = rsqrtf(ss * (1.0f / D_MODEL) + 1e-6f);
  const float4 wa = *(const float4*)(w + lane * 8);
  const float4 wb = *(const float4*)(w + lane * 8 + 4);
  short8 o;
  o[0] = f2bf(a.x * scale * wa.x);
  o[1] = f2bf(a.y * scale * wa.y);
  o[2] = f2bf(a.z * scale * wa.z);
  o[3] = f2bf(a.w * scale * wa.w);
  o[4] = f2bf(b.x * scale * wb.x);
  o[5] = f2bf(b.y * scale * wb.y);
  o[6] = f2bf(b.z * scale * wb.z);
  o[7] = f2bf(b.w * scale * wb.w);
  *(short8*)(outp + row * D_MODEL + lane * 8) = o;
}

// ---------- causal depthwise conv (K=17, dilation=1), bf16 in/out ----------
__global__ void dwconv_kernel(const short* __restrict__ hn, const float* __restrict__ wT,
                              short* __restrict__ hc) {
  const int tid = threadIdx.x;
  const int chunk = tid & 63;                       // 64 chunks of 8 channels
  const long row = (long)blockIdx.x * 4 + (tid >> 6);
  const int t = (int)(row & (TSEQ - 1));
  const int c0 = chunk * 8;
  float acc[8];
#pragma unroll
  for (int j = 0; j < 8; ++j) acc[j] = 0.f;
  const int kmin = (t >= 16) ? 0 : (16 - t);
  for (int k = kmin; k < 17; ++k) {
    const short8 h = *(const short8*)(hn + (row - 16 + k) * D_MODEL + c0);
    const float* wp = wT + k * D_MODEL + c0;
    const float4 w0 = *(const float4*)(wp);
    const float4 w1 = *(const float4*)(wp + 4);
    acc[0] += bf2f(h[0]) * w0.x;
    acc[1] += bf2f(h[1]) * w0.y;
    acc[2] += bf2f(h[2]) * w0.z;
    acc[3] += bf2f(h[3]) * w0.w;
    acc[4] += bf2f(h[4]) * w1.x;
    acc[5] += bf2f(h[5]) * w1.y;
    acc[6] += bf2f(h[6]) * w1.z;
    acc[7] += bf2f(h[7]) * w1.w;
  }
  short8 o;
#pragma unroll
  for (int j = 0; j < 8; ++j) o[j] = f2bf(acc[j]);
  *(short8*)(hc + row * D_MODEL + c0) = o;
}

// ---------- 256x256 8-phase GEMM, 32x32x16 MFMA ----------
// C[M][N] = A[M][K](bf16) x Bt[N][K](bf16). 512 threads = 8 waves (2M x 4N),
// wave tile 128x64 = 4 m-blocks x 2 n-blocks of 32x32. BK=64 -> 4 k-slices of 16.
// LDS 128 KiB = 2 tile-buffers x (A 256x64 + B 256x64). Phase schedule, staging,
// counted-vmcnt, and both-sides XOR swizzle identical to R3/R4 (0 conflicts measured).
// 32x32x16: A lane l holds row=l&31, k=(l>>5)*8+j (2xK doubling, same rule validated
// on 16x16x32); C/D: col=lane&31, row=(reg&3)+8*(reg>>2)+4*(lane>>5) (m74/m101).
#define PHASE_BAR() __builtin_amdgcn_s_barrier()
#define LGKM0() { asm volatile("s_waitcnt lgkmcnt(0)" ::: "memory"); __builtin_amdgcn_sched_barrier(0); }
#define LGKM4() { asm volatile("s_waitcnt lgkmcnt(4)" ::: "memory"); __builtin_amdgcn_sched_barrier(0); }
#define VMC4()  { asm volatile("s_waitcnt vmcnt(4)" ::: "memory"); __builtin_amdgcn_sched_barrier(0); }
#define VMC0()  { asm volatile("s_waitcnt vmcnt(0)" ::: "memory"); __builtin_amdgcn_sched_barrier(0); }
// asm ds_read_b128: dst 4-VGPR tuple, addr VGPR, literal byte offset
#define DSR1(dst, addr, imm) \
  asm volatile("ds_read_b128 %0, %1 offset:%2" : "=v"(dst) : "v"(addr), "i"(imm))

template <int EPI>
__global__ __launch_bounds__(512, 2)
void gemm256(const short* __restrict__ A, const short* __restrict__ Bt,
             const int K, const int N, const int nbn,
             const void* __restrict__ aux, void* __restrict__ outp) {
  __shared__ short Alds[2 * 2 * 128 * 64];   // [buf][half][row 128][k 64]
  __shared__ short Blds[2 * 2 * 128 * 64];
  const int tid = threadIdx.x;
  const int lane = tid & 63;
  const int w = tid >> 6;
  const int wm = w >> 2;          // 0..1  (M half of block)
  const int wn = w & 3;           // 0..3  (N quarter of block)

  // XCD-chunked swizzle (all call sites have gridDim.x % 8 == 0)
  const int nwg = gridDim.x;
  const int cpx = nwg >> 3;
  const int bid = blockIdx.x;
  const int wid = (bid & 7) * cpx + (bid >> 3);
  const long brow = (long)(wid / nbn) * 256;
  const long bcol = (long)(wid % nbn) * 256;

  floatx16 acc[4][2];
#pragma unroll
  for (int i = 0; i < 4; ++i)
#pragma unroll
    for (int j = 0; j < 2; ++j)
#pragma unroll
      for (int e = 0; e < 16; ++e) acc[i][j][e] = 0.f;

  short8 af[2][4];   // A frags: 2 m-blocks (current pair) x 4 k-slices
  short8 bfr[2][4];  // B frags: 2 n-blocks x 4 k-slices (whole tile, held in regs)

  // staging addresses: pre-swizzled global chunk, linear LDS dest
  const int chunkx = (lane & 7) ^ (lane >> 3);
  const short* gA = A + (brow + w * 8 + (lane >> 3)) * (long)K + chunkx * 8;
  const short* gB = Bt + (bcol + w * 8 + (lane >> 3)) * (long)K + chunkx * 8;

  // ds_read addresses: frag byte = buf*32768 + half*16384 + r*128 + c*16
  //   r = block*32 + (lane&31), c = (ks*2 + (lane>>5)) ^ (lane&7)   [r&7 == lane&7]
  // addr = base + half*16384 + (lane&31)*128 + c(ks)*16 ; imm = buf*32768 + block*4096
  const unsigned Abase = (unsigned)(uintptr_t)(__attribute__((address_space(3))) short*)Alds;
  const unsigned Bbase = (unsigned)(uintptr_t)(__attribute__((address_space(3))) short*)Blds;
  const unsigned lane31 = (unsigned)((lane & 31) * 128);
  const unsigned khi = (unsigned)(lane >> 5);
  const unsigned lxor = (unsigned)(lane & 7);
  const unsigned c0t = ((0u * 2 + khi) ^ lxor) * 16;
  const unsigned c1t = ((1u * 2 + khi) ^ lxor) * 16;
  const unsigned c2t = ((2u * 2 + khi) ^ lxor) * 16;
  const unsigned c3t = ((3u * 2 + khi) ^ lxor) * 16;
  const unsigned aoff = Abase + (unsigned)(wm * 16384) + lane31;
  const unsigned boff = Bbase + (unsigned)((wn >> 1) * 16384 + (wn & 1) * 8192) + lane31;
  const unsigned adrA0 = aoff + c0t, adrA1 = aoff + c1t, adrA2 = aoff + c2t, adrA3 = aoff + c3t;
  const unsigned adrB0 = boff + c0t, adrB1 = boff + c1t, adrB2 = boff + c2t, adrB3 = boff + c3t;

#define STGA(half, BUF, koff)                                                  \
  { _Pragma("unroll")                                                          \
    for (int j = 0; j < 2; ++j)                                                \
      gload_lds16(gA + ((half) * 128 + j * 64) * (long)K + (koff),             \
                  &Alds[(((BUF) * 2 + (half)) * 128 + j * 64 + w * 8) * 64]); }
#define STGB(half, BUF, koff)                                                  \
  { _Pragma("unroll")                                                          \
    for (int j = 0; j < 2; ++j)                                                \
      gload_lds16(gB + ((half) * 128 + j * 64) * (long)K + (koff),             \
                  &Blds[(((BUF) * 2 + (half)) * 128 + j * 64 + w * 8) * 64]); }

#define LDA32(mbase, BUF) {                                                    \
    DSR1(af[0][0], adrA0, (BUF)*32768 + ((mbase)+0)*4096);                     \
    DSR1(af[0][1], adrA1, (BUF)*32768 + ((mbase)+0)*4096);                     \
    DSR1(af[0][2], adrA2, (BUF)*32768 + ((mbase)+0)*4096);                     \
    DSR1(af[0][3], adrA3, (BUF)*32768 + ((mbase)+0)*4096);                     \
    DSR1(af[1][0], adrA0, (BUF)*32768 + ((mbase)+1)*4096);                     \
    DSR1(af[1][1], adrA1, (BUF)*32768 + ((mbase)+1)*4096);                     \
    DSR1(af[1][2], adrA2, (BUF)*32768 + ((mbase)+1)*4096);                     \
    DSR1(af[1][3], adrA3, (BUF)*32768 + ((mbase)+1)*4096); }
#define LDB32(nb, BUF) {                                                       \
    DSR1(bfr[nb][0], adrB0, (BUF)*32768 + (nb)*4096);                          \
    DSR1(bfr[nb][1], adrB1, (BUF)*32768 + (nb)*4096);                          \
    DSR1(bfr[nb][2], adrB2, (BUF)*32768 + (nb)*4096);                          \
    DSR1(bfr[nb][3], adrB3, (BUF)*32768 + (nb)*4096); }

#define MMACL32(mbase, nb)                                                     \
  { __builtin_amdgcn_s_setprio(1);                                             \
    _Pragma("unroll")                                                          \
    for (int i = 0; i < 2; ++i)                                                \
      _Pragma("unroll")                                                        \
      for (int ks = 0; ks < 4; ++ks)                                           \
        acc[(mbase) + i][nb] = __builtin_amdgcn_mfma_f32_32x32x16_bf16(        \
            af[i][ks], bfr[nb][ks], acc[(mbase) + i][nb], 0, 0, 0);            \
    __builtin_amdgcn_s_setprio(0); }

  // TILE: DOST01 stages A0/A1(t+1) at q0/q1; DOST23 stages B0/B1(t+2) at q2/q3.
  // Per-tile vmcnt AFTER q3's MFMA cluster (wait overlapped by compute).
#define TILE(BUF, DOST01, DOST23, W4, W0, kA, kB)                              \
  {                                                                            \
    /* q0: m-blocks 0-1 x n-block 0 */                                         \
    LDA32(0, BUF); LDB32(0, BUF);                                              \
    if (DOST01) STGA(0, (BUF) ^ 1, kA);                                        \
    LGKM4();                                                                   \
    PHASE_BAR(); LGKM0(); MMACL32(0, 0); PHASE_BAR();                          \
    /* q1: m 0-1 x n 1 */                                                      \
    LDB32(1, BUF);                                                             \
    if (DOST01) STGA(1, (BUF) ^ 1, kA);                                        \
    PHASE_BAR(); LGKM0(); MMACL32(0, 1); PHASE_BAR();                          \
    /* q2: m 2-3 x n 0 */                                                      \
    LDA32(2, BUF);                                                             \
    if (DOST23) STGB(0, BUF, kB);                                              \
    PHASE_BAR(); LGKM0(); MMACL32(2, 0); PHASE_BAR();                          \
    /* q3: m 2-3 x n 1 */                                                      \
    if (DOST23) STGB(1, BUF, kB);                                              \
    PHASE_BAR(); MMACL32(2, 1);                                                \
    if (W4) VMC4();                                                            \
    if (W0) VMC0();                                                            \
    PHASE_BAR();                                                               \
  }

  // prologue: stream order B0(0),B1(0),A0(0),A1(0),B0(1),B1(1); leave tile1 B's in flight
  STGB(0, 0, 0); STGB(1, 0, 0); STGA(0, 0, 0); STGA(1, 0, 0);
  STGB(0, 1, 64); STGB(1, 1, 64);
  VMC4(); PHASE_BAR();

  const int nkt = K >> 6;          // 8 or 32 at our call sites (even, >= 8)
  int kA = 64, kB = 128;
  for (int t = 0; t < nkt - 2; t += 2) {
    TILE(0, 1, 1, 1, 0, kA, kB); kA += 64; kB += 64;
    TILE(1, 1, 1, 1, 0, kA, kB); kA += 64; kB += 64;
  }
  TILE(0, 1, 0, 0, 1, kA, 0);      // tile nkt-2: stage A(nkt-1) only, then full drain
  TILE(1, 0, 0, 0, 0, 0, 0);       // tile nkt-1: pure compute

#undef TILE
#undef MMACL32
#undef LDA32
#undef LDB32
#undef STGA
#undef STGB

  // epilogue: 32x32 C/D layout col=lane&31, row=(reg&3)+8*(reg>>2)+4*(lane>>5)
  // 32-bit index math (max idx = 65536*2048 < 2^31).
#pragma unroll
  for (int mb = 0; mb < 4; ++mb) {
#pragma unroll
    for (int nb = 0; nb < 2; ++nb) {
      const int col = (int)bcol + wn * 64 + nb * 32 + (lane & 31);
      const int rbase = (int)brow + wm * 128 + mb * 32 + ((lane >> 5) << 2);
#pragma unroll
      for (int reg = 0; reg < 16; ++reg) {
        const int row = rbase + (reg & 3) + ((reg >> 2) << 3);
        const int idx = row * N + col;
        const float v = acc[mb][nb][reg];
        if (EPI == 0) {
          const float hcv = bf2f(((const short*)aux)[idx]);
          const float g = 1.f / (1.f + __expf(-v));
          ((short*)outp)[idx] = f2bf(g * hcv);
        } else if (EPI == 1) {
          ((float*)outp)[idx] = ((const float*)aux)[idx] + v;
        } else if (EPI == 2) {
          const float x3 = v * v * v;
          const float z = 0.7978845608028654f * (v + 0.044715f * x3);
          const float th = 1.f - 2.f / (__expf(2.f * z) + 1.f);   // tanh(z)
          ((short*)outp)[idx] = f2bf(0.5f * v * (1.f + th));
        } else {
          ((float*)outp)[idx] += v;
        }
      }
    }
  }
}

// ---------- launch ----------
extern "C" void kernel_launch(void* const* d_in, const int* in_sizes, int n_in,
                              void* d_out, int out_size, void* d_ws, size_t ws_size,
                              hipStream_t stream) {
  const float* x      = (const float*)d_in[0];
  const float* ln1_w  = (const float*)d_in[1];
  const float* gate_w = (const float*)d_in[2];   // [512][512]
  const float* conv_w = (const float*)d_in[3];   // [512][17]
  const float* proj_w = (const float*)d_in[4];   // [512][512]
  const float* ln2_w  = (const float*)d_in[5];
  const float* mlp_w1 = (const float*)d_in[6];   // [512][2048]
  const float* mlp_w2 = (const float*)d_in[7];   // [2048][512]
  float* out = (float*)d_out;
  char* ws = (char*)d_ws;

  // workspace layout (bytes), all offsets 256B-aligned
  short* hn      = (short*)(ws + 0);                       // 64 MiB  (also hn2 later)
  short* hc      = (short*)(ws + 67108864L);               // 64 MiB  (hc, then u in-place)
  short* mid     = (short*)(ws + 134217728L);              // 256 MiB
  short* gate_wt = (short*)(ws + 402653184L);              // 512 KiB [512][512]
  short* proj_wt = (short*)(ws + 403177472L);              // 512 KiB
  short* w1t     = (short*)(ws + 403701760L);              // 2 MiB   [2048][512]
  short* w2t     = (short*)(ws + 405798912L);              // 2 MiB   [512][2048]
  float* convwT  = (float*)(ws + 407896064L);              // 34 KiB  [17][512]

  const dim3 b256(256);
  const dim3 b512(512);

  // weights -> bf16 transposed (per-call; deterministic, ~5 MB)
  wt_transpose<<<dim3(8, 8),  b256, 0, stream>>>(gate_w, gate_wt, 512, 512);
  wt_transpose<<<dim3(8, 8),  b256, 0, stream>>>(proj_w, proj_wt, 512, 512);
  wt_transpose<<<dim3(8, 32), b256, 0, stream>>>(mlp_w1, w1t, 512, 2048);
  wt_transpose<<<dim3(32, 8), b256, 0, stream>>>(mlp_w2, w2t, 2048, 512);
  convw_transpose<<<34, b256, 0, stream>>>(conv_w, convwT);

  // 1) hn = rmsnorm(x, ln1_w)
  rmsnorm_kernel<<<NTOK / 4, b256, 0, stream>>>(x, ln1_w, hn);
  // 2) hc = causal_dwconv(hn)
  dwconv_kernel<<<NTOK / 4, b256, 0, stream>>>(hn, convwT, hc);
  // 3) u = sigmoid(hn @ gate_w) * hc   (in-place into hc)
  gemm256<0><<<256 * 2, b512, 0, stream>>>(hn, gate_wt, 512, 512, 2, hc, hc);
  // 4) x2 = x + u @ proj_w  -> d_out (f32)
  gemm256<1><<<256 * 2, b512, 0, stream>>>(hc, proj_wt, 512, 512, 2, x, out);
  // 5) hn2 = rmsnorm(x2, ln2_w)  (reuse hn buffer)
  rmsnorm_kernel<<<NTOK / 4, b256, 0, stream>>>(out, ln2_w, hn);
  // 6) mid = gelu(hn2 @ mlp_w1)
  gemm256<2><<<256 * 8, b512, 0, stream>>>(hn, w1t, 512, 2048, 8, nullptr, mid);
  // 7) out += mid @ mlp_w2
  gemm256<3><<<256 * 2, b512, 0, stream>>>(mid, w2t, 2048, 512, 2, nullptr, out);
}

// Round 6
// 692.484 us; speedup vs baseline: 1.1638x; 1.1638x over previous
//
#include <hip/hip_runtime.h>
#include <hip/hip_bf16.h>
#include <cstdint>
#include <cstddef>

// ---------- types ----------
typedef __attribute__((ext_vector_type(8))) short short8;   // bf16 x8 (4 VGPRs)
typedef __attribute__((ext_vector_type(4))) short short4v;  // bf16 x4
typedef __attribute__((ext_vector_type(4))) float floatx4;

#define D_MODEL 512
#define HDIM    2048
#define TSEQ    16384
#define NTOK    65536   // B*T = 4*16384

// ---------- helpers ----------
__device__ __forceinline__ float bf2f(short s) {
  union { unsigned u; float f; } v; v.u = ((unsigned)(unsigned short)s) << 16; return v.f;
}
__device__ __forceinline__ short f2bf(float f) {
  union { float fv; unsigned u; } v; v.fv = f;
  unsigned u = v.u;
  u += 0x7FFFu + ((u >> 16) & 1u);   // RNE
  return (short)(u >> 16);
}
__device__ __forceinline__ void gload_lds16(const void* g, void* l) {
  // width=16 async global->LDS; LDS dest = wave-uniform base + lane*16 (m104)
  __builtin_amdgcn_global_load_lds((const __attribute__((address_space(1))) void*)g,
                                   (__attribute__((address_space(3))) void*)l, 16, 0, 0);
}

// ---------- weight convert + transpose: W[K][N] f32 -> Wt[N][K] bf16 ----------
__global__ void wt_transpose(const float* __restrict__ W, short* __restrict__ Wt,
                             const int K, const int N) {
  __shared__ float t[64][65];
  const int tid = threadIdx.x;
  const long k0 = (long)blockIdx.x * 64;
  const long n0 = (long)blockIdx.y * 64;
  const int rr = tid >> 4;
  const int cc = (tid & 15) * 4;
#pragma unroll
  for (int i = 0; i < 4; ++i) {
    const int r = rr + i * 16;
    const float4 v = *(const float4*)(W + (k0 + r) * N + n0 + cc);
    t[r][cc + 0] = v.x; t[r][cc + 1] = v.y; t[r][cc + 2] = v.z; t[r][cc + 3] = v.w;
  }
  __syncthreads();
#pragma unroll
  for (int i = 0; i < 4; ++i) {
    const int n = rr + i * 16;
    short4v o;
    o[0] = f2bf(t[cc + 0][n]);
    o[1] = f2bf(t[cc + 1][n]);
    o[2] = f2bf(t[cc + 2][n]);
    o[3] = f2bf(t[cc + 3][n]);
    *(short4v*)(Wt + (n0 + n) * K + k0 + cc) = o;
  }
}

// conv_w [512][17] f32 -> wT [17][512] f32
__global__ void convw_transpose(const float* __restrict__ cw, float* __restrict__ wT) {
  const int idx = blockIdx.x * 256 + threadIdx.x;
  if (idx >= 17 * D_MODEL) return;
  const int k = idx / D_MODEL;
  const int c = idx % D_MODEL;
  wT[idx] = cw[c * 17 + k];
}

// ---------- RMSNorm: one wave per row, f32 in -> bf16 out ----------
__global__ void rmsnorm_kernel(const float* __restrict__ x, const float* __restrict__ w,
                               short* __restrict__ outp) {
  const int lane = threadIdx.x & 63;
  const long row = (long)blockIdx.x * 4 + (threadIdx.x >> 6);
  const float* xr = x + row * D_MODEL + lane * 8;
  const float4 a = *(const float4*)xr;
  const float4 b = *(const float4*)(xr + 4);
  float ss = a.x * a.x + a.y * a.y + a.z * a.z + a.w * a.w
           + b.x * b.x + b.y * b.y + b.z * b.z + b.w * b.w;
#pragma unroll
  for (int m = 32; m; m >>= 1) ss += __shfl_xor(ss, m);
  const float scale = rsqrtf(ss * (1.0f / D_MODEL) + 1e-6f);
  const float4 wa = *(const float4*)(w + lane * 8);
  const float4 wb = *(const float4*)(w + lane * 8 + 4);
  short8 o;
  o[0] = f2bf(a.x * scale * wa.x);
  o[1] = f2bf(a.y * scale * wa.y);
  o[2] = f2bf(a.z * scale * wa.z);
  o[3] = f2bf(a.w * scale * wa.w);
  o[4] = f2bf(b.x * scale * wb.x);
  o[5] = f2bf(b.y * scale * wb.y);
  o[6] = f2bf(b.z * scale * wb.z);
  o[7] = f2bf(b.w * scale * wb.w);
  *(short8*)(outp + row * D_MODEL + lane * 8) = o;
}

// ---------- causal depthwise conv (K=17, dilation=1), bf16 in/out ----------
__global__ void dwconv_kernel(const short* __restrict__ hn, const float* __restrict__ wT,
                              short* __restrict__ hc) {
  const int tid = threadIdx.x;
  const int chunk = tid & 63;                       // 64 chunks of 8 channels
  const long row = (long)blockIdx.x * 4 + (tid >> 6);
  const int t = (int)(row & (TSEQ - 1));
  const int c0 = chunk * 8;
  float acc[8];
#pragma unroll
  for (int j = 0; j < 8; ++j) acc[j] = 0.f;
  const int kmin = (t >= 16) ? 0 : (16 - t);
  for (int k = kmin; k < 17; ++k) {
    const short8 h = *(const short8*)(hn + (row - 16 + k) * D_MODEL + c0);
    const float* wp = wT + k * D_MODEL + c0;
    const float4 w0 = *(const float4*)(wp);
    const float4 w1 = *(const float4*)(wp + 4);
    acc[0] += bf2f(h[0]) * w0.x;
    acc[1] += bf2f(h[1]) * w0.y;
    acc[2] += bf2f(h[2]) * w0.z;
    acc[3] += bf2f(h[3]) * w0.w;
    acc[4] += bf2f(h[4]) * w1.x;
    acc[5] += bf2f(h[5]) * w1.y;
    acc[6] += bf2f(h[6]) * w1.z;
    acc[7] += bf2f(h[7]) * w1.w;
  }
  short8 o;
#pragma unroll
  for (int j = 0; j < 8; ++j) o[j] = f2bf(acc[j]);
  *(short8*)(hc + row * D_MODEL + c0) = o;
}

// ---------- 256x256 GEMM, 16x16x32 MFMA, de-lockstepped 2-barrier tiles ----------
// C[M][N] = A[M][K](bf16) x Bt[N][K](bf16). 512 threads = 8 waves (2M x 4N),
// wave tile 128x64. BK=64. LDS 128 KiB = 2 tile-buffers x (A 256x64 + B 256x64).
// Per K-tile (waves SELF-PACED between barriers):
//   top:  stage A(t+1)->buf^1; 16 ds_read (A m0-3 + B n0-3); lgkm0; 32 MFMA
//   MID-BARRIER  (all waves' B(t)-reads complete -> B-half WAR safe)
//   stage B(t+2)->buf; 8 ds_read (A m4-7); lgkm0; 32 MFMA; vmcnt(4)
//   END-BARRIER  (A(t+1)/B(t+1) DMA complete for ALL waves; buf-swap WAR safe)
// Hazards: every stage lands >=1 barrier after its region's last read; every read
// >=1 vmcnt+barrier after its DMA issue. vmcnt(4)@end leaves exactly B(t+2) in flight.
// Frag reads are inline-asm ds_read_b128 (defeats conservative vmcnt(0) on LDS-DMA
// alias; rule #18 sched_barrier(0) after each manual waitcnt). Both-sides XOR chunk
// swizzle (16x16 pattern) -> 0 bank conflicts measured (R1-R4).
#define PHASE_BAR() __builtin_amdgcn_s_barrier()
#define LGKM0() { asm volatile("s_waitcnt lgkmcnt(0)" ::: "memory"); __builtin_amdgcn_sched_barrier(0); }
#define VMC4()  { asm volatile("s_waitcnt vmcnt(4)" ::: "memory"); __builtin_amdgcn_sched_barrier(0); }
#define VMC0()  { asm volatile("s_waitcnt vmcnt(0)" ::: "memory"); __builtin_amdgcn_sched_barrier(0); }
// asm ds_read_b128: dst 4-VGPR tuple, addr VGPR, literal byte offset
#define DSR1(dst, addr, imm) \
  asm volatile("ds_read_b128 %0, %1 offset:%2" : "=v"(dst) : "v"(addr), "i"(imm))

template <int EPI>
__global__ __launch_bounds__(512, 2)
void gemm256(const short* __restrict__ A, const short* __restrict__ Bt,
             const int K, const int N, const int nbn,
             const void* __restrict__ aux, void* __restrict__ outp) {
  __shared__ short Alds[2 * 2 * 128 * 64];   // [buf][half][row 128][k 64]
  __shared__ short Blds[2 * 2 * 128 * 64];
  const int tid = threadIdx.x;
  const int lane = tid & 63;
  const int w = tid >> 6;
  const int wm = w >> 2;          // 0..1  (M half of block)
  const int wn = w & 3;           // 0..3  (N quarter of block)

  // XCD-chunked swizzle (all call sites have gridDim.x % 8 == 0)
  const int nwg = gridDim.x;
  const int cpx = nwg >> 3;
  const int bid = blockIdx.x;
  const int wid = (bid & 7) * cpx + (bid >> 3);
  const long brow = (long)(wid / nbn) * 256;
  const long bcol = (long)(wid % nbn) * 256;

  floatx4 acc[8][4];
#pragma unroll
  for (int i = 0; i < 8; ++i)
#pragma unroll
    for (int j = 0; j < 4; ++j) acc[i][j] = {0.f, 0.f, 0.f, 0.f};

  short8 af[4][2];   // A frags: 4 m-frags x 2 k-slices (rows mbase..mbase+3)
  short8 bfr[4][2];  // B frags: 4 n-frags x 2 k-slices (whole tile, held in regs)

  // staging addresses: pre-swizzled global chunk, linear LDS dest
  const int chunkx = (lane & 7) ^ (lane >> 3);
  const short* gA = A + (brow + w * 8 + (lane >> 3)) * (long)K + chunkx * 8;
  const short* gB = Bt + (bcol + w * 8 + (lane >> 3)) * (long)K + chunkx * 8;
  const int kchunk = lane >> 4;   // 0..3

  // ds_read base addresses (16x16 pattern, 0-conflict verified R1-R4):
  // frag byte = BUF*32768 + half*16384 + r*128 + c*16, r=(mbase+mi)*16+(lane&15),
  //   c=(ks*4+kchunk)^(lane&7)
  const unsigned Abase = (unsigned)(uintptr_t)(__attribute__((address_space(3))) short*)Alds;
  const unsigned Bbase = (unsigned)(uintptr_t)(__attribute__((address_space(3))) short*)Blds;
  const unsigned lanelo = (unsigned)((lane & 15) * 128);
  const unsigned c0t = (unsigned)(((0 + kchunk) ^ (lane & 7)) * 16);
  const unsigned c1t = (unsigned)(((4 + kchunk) ^ (lane & 7)) * 16);
  const unsigned adrA0 = Abase + (unsigned)(wm * 16384) + lanelo + c0t;
  const unsigned adrA1 = Abase + (unsigned)(wm * 16384) + lanelo + c1t;
  const unsigned adrB0 = Bbase + (unsigned)((wn >> 1) * 16384 + (wn & 1) * 8192) + lanelo + c0t;
  const unsigned adrB1 = Bbase + (unsigned)((wn >> 1) * 16384 + (wn & 1) * 8192) + lanelo + c1t;

#define STGA(half, BUF, koff)                                                  \
  { _Pragma("unroll")                                                          \
    for (int j = 0; j < 2; ++j)                                                \
      gload_lds16(gA + ((half) * 128 + j * 64) * (long)K + (koff),             \
                  &Alds[(((BUF) * 2 + (half)) * 128 + j * 64 + w * 8) * 64]); }
#define STGB(half, BUF, koff)                                                  \
  { _Pragma("unroll")                                                          \
    for (int j = 0; j < 2; ++j)                                                \
      gload_lds16(gB + ((half) * 128 + j * 64) * (long)K + (koff),             \
                  &Blds[(((BUF) * 2 + (half)) * 128 + j * 64 + w * 8) * 64]); }

#define LDA4(mbase, BUF) {                                                     \
    DSR1(af[0][0], adrA0, (BUF)*32768 + ((mbase)+0)*2048);                     \
    DSR1(af[0][1], adrA1, (BUF)*32768 + ((mbase)+0)*2048);                     \
    DSR1(af[1][0], adrA0, (BUF)*32768 + ((mbase)+1)*2048);                     \
    DSR1(af[1][1], adrA1, (BUF)*32768 + ((mbase)+1)*2048);                     \
    DSR1(af[2][0], adrA0, (BUF)*32768 + ((mbase)+2)*2048);                     \
    DSR1(af[2][1], adrA1, (BUF)*32768 + ((mbase)+2)*2048);                     \
    DSR1(af[3][0], adrA0, (BUF)*32768 + ((mbase)+3)*2048);                     \
    DSR1(af[3][1], adrA1, (BUF)*32768 + ((mbase)+3)*2048); }
#define LDB2(nbase, BUF) {                                                     \
    DSR1(bfr[(nbase)+0][0], adrB0, (BUF)*32768 + ((nbase)+0)*2048);            \
    DSR1(bfr[(nbase)+0][1], adrB1, (BUF)*32768 + ((nbase)+0)*2048);            \
    DSR1(bfr[(nbase)+1][0], adrB0, (BUF)*32768 + ((nbase)+1)*2048);            \
    DSR1(bfr[(nbase)+1][1], adrB1, (BUF)*32768 + ((nbase)+1)*2048); }

#define MMACL(mbase, nbase)                                                    \
  { __builtin_amdgcn_s_setprio(1);                                             \
    _Pragma("unroll")                                                          \
    for (int mi = 0; mi < 4; ++mi)                                             \
      _Pragma("unroll")                                                        \
      for (int nn = 0; nn < 2; ++nn)                                           \
        _Pragma("unroll")                                                      \
        for (int ks = 0; ks < 2; ++ks)                                         \
          acc[(mbase) + mi][(nbase) + nn] = __builtin_amdgcn_mfma_f32_16x16x32_bf16( \
              af[mi][ks], bfr[(nbase) + nn][ks], acc[(mbase) + mi][(nbase) + nn], 0, 0, 0); \
    __builtin_amdgcn_s_setprio(0); }

  // TILE: DOSTA stages A(t+1)->BUF^1 at top; DOSTB stages B(t+2)->BUF at mid.
  // W4: vmcnt(4) before end-barrier (steady); W0: vmcnt(0) (tail drain).
  // LASTT: last tile -> skip barriers entirely.
#define TILE(BUF, DOSTA, DOSTB, W4, W0, LASTT, kA, kB)                         \
  {                                                                            \
    if (DOSTA) { STGA(0, (BUF) ^ 1, kA); STGA(1, (BUF) ^ 1, kA); }             \
    LDA4(0, BUF); LDB2(0, BUF); LDB2(2, BUF);                                  \
    LGKM0();                                                                   \
    MMACL(0, 0); MMACL(0, 2);                                                  \
    if (!LASTT) PHASE_BAR();      /* mid: all B(t)-reads done */               \
    if (DOSTB) { STGB(0, BUF, kB); STGB(1, BUF, kB); }                         \
    LDA4(4, BUF);                                                              \
    LGKM0();                                                                   \
    MMACL(4, 0); MMACL(4, 2);                                                  \
    if (W4) VMC4();                                                            \
    if (W0) VMC0();                                                            \
    if (!LASTT) PHASE_BAR();      /* end: DMA(t+1) visible; buf-swap safe */   \
  }

  // prologue: A(0), B(0), B(1); wait oldest 8 (A0,B0) done, leave B(1) in flight
  STGA(0, 0, 0); STGA(1, 0, 0);
  STGB(0, 0, 0); STGB(1, 0, 0);
  STGB(0, 1, 64); STGB(1, 1, 64);
  VMC4(); PHASE_BAR();

  const int nkt = K >> 6;          // 8 or 32 at our call sites (even, >= 8)
  int kA = 64, kB = 128;
  for (int t = 0; t < nkt - 2; t += 2) {
    TILE(0, 1, 1, 1, 0, 0, kA, kB); kA += 64; kB += 64;
    TILE(1, 1, 1, 1, 0, 0, kA, kB); kA += 64; kB += 64;
  }
  TILE(0, 1, 0, 0, 1, 0, kA, 0);   // tile nkt-2: stage A(nkt-1) only, full drain
  TILE(1, 0, 0, 0, 0, 1, 0, 0);    // tile nkt-1: pure compute, no barriers

#undef TILE
#undef MMACL
#undef LDA4
#undef LDB2
#undef STGA
#undef STGB

  // epilogue: C/D layout col=lane&15, row=(lane>>4)*4+j. 32-bit index math.
#pragma unroll
  for (int mi = 0; mi < 8; ++mi) {
    const int r0 = (int)brow + wm * 128 + mi * 16 + (lane >> 4) * 4;
#pragma unroll
    for (int j = 0; j < 4; ++j) {
      const int rb = (r0 + j) * N;
      const int gcb = (int)bcol + wn * 64 + (lane & 15);
#pragma unroll
      for (int ni = 0; ni < 4; ++ni) {
        const int idx = rb + gcb + ni * 16;
        const float v = acc[mi][ni][j];
        if (EPI == 0) {
          const float hcv = bf2f(((const short*)aux)[idx]);
          const float g = 1.f / (1.f + __expf(-v));
          ((short*)outp)[idx] = f2bf(g * hcv);
        } else if (EPI == 1) {
          ((float*)outp)[idx] = ((const float*)aux)[idx] + v;
        } else if (EPI == 2) {
          const float x3 = v * v * v;
          const float z = 0.7978845608028654f * (v + 0.044715f * x3);
          const float th = 1.f - 2.f / (__expf(2.f * z) + 1.f);   // tanh(z)
          ((short*)outp)[idx] = f2bf(0.5f * v * (1.f + th));
        } else {
          ((float*)outp)[idx] += v;
        }
      }
    }
  }
}

// ---------- launch ----------
extern "C" void kernel_launch(void* const* d_in, const int* in_sizes, int n_in,
                              void* d_out, int out_size, void* d_ws, size_t ws_size,
                              hipStream_t stream) {
  const float* x      = (const float*)d_in[0];
  const float* ln1_w  = (const float*)d_in[1];
  const float* gate_w = (const float*)d_in[2];   // [512][512]
  const float* conv_w = (const float*)d_in[3];   // [512][17]
  const float* proj_w = (const float*)d_in[4];   // [512][512]
  const float* ln2_w  = (const float*)d_in[5];
  const float* mlp_w1 = (const float*)d_in[6];   // [512][2048]
  const float* mlp_w2 = (const float*)d_in[7];   // [2048][512]
  float* out = (float*)d_out;
  char* ws = (char*)d_ws;

  // workspace layout (bytes), all offsets 256B-aligned
  short* hn      = (short*)(ws + 0);                       // 64 MiB  (also hn2 later)
  short* hc      = (short*)(ws + 67108864L);               // 64 MiB  (hc, then u in-place)
  short* mid     = (short*)(ws + 134217728L);              // 256 MiB
  short* gate_wt = (short*)(ws + 402653184L);              // 512 KiB [512][512]
  short* proj_wt = (short*)(ws + 403177472L);              // 512 KiB
  short* w1t     = (short*)(ws + 403701760L);              // 2 MiB   [2048][512]
  short* w2t     = (short*)(ws + 405798912L);              // 2 MiB   [512][2048]
  float* convwT  = (float*)(ws + 407896064L);              // 34 KiB  [17][512]

  const dim3 b256(256);
  const dim3 b512(512);

  // weights -> bf16 transposed (per-call; deterministic, ~5 MB)
  wt_transpose<<<dim3(8, 8),  b256, 0, stream>>>(gate_w, gate_wt, 512, 512);
  wt_transpose<<<dim3(8, 8),  b256, 0, stream>>>(proj_w, proj_wt, 512, 512);
  wt_transpose<<<dim3(8, 32), b256, 0, stream>>>(mlp_w1, w1t, 512, 2048);
  wt_transpose<<<dim3(32, 8), b256, 0, stream>>>(mlp_w2, w2t, 2048, 512);
  convw_transpose<<<34, b256, 0, stream>>>(conv_w, convwT);

  // 1) hn = rmsnorm(x, ln1_w)
  rmsnorm_kernel<<<NTOK / 4, b256, 0, stream>>>(x, ln1_w, hn);
  // 2) hc = causal_dwconv(hn)
  dwconv_kernel<<<NTOK / 4, b256, 0, stream>>>(hn, convwT, hc);
  // 3) u = sigmoid(hn @ gate_w) * hc   (in-place into hc)
  gemm256<0><<<256 * 2, b512, 0, stream>>>(hn, gate_wt, 512, 512, 2, hc, hc);
  // 4) x2 = x + u @ proj_w  -> d_out (f32)
  gemm256<1><<<256 * 2, b512, 0, stream>>>(hc, proj_wt, 512, 512, 2, x, out);
  // 5) hn2 = rmsnorm(x2, ln2_w)  (reuse hn buffer)
  rmsnorm_kernel<<<NTOK / 4, b256, 0, stream>>>(out, ln2_w, hn);
  // 6) mid = gelu(hn2 @ mlp_w1)
  gemm256<2><<<256 * 8, b512, 0, stream>>>(hn, w1t, 512, 2048, 8, nullptr, mid);
  // 7) out += mid @ mlp_w2
  gemm256<3><<<256 * 2, b512, 0, stream>>>(mid, w2t, 2048, 512, 2, nullptr, out);
}